// Round 2
// baseline (315.682 us; speedup 1.0000x reference)
//
#include <hip/hip_runtime.h>
#include <hip/hip_bf16.h>
#include <math.h>

typedef short bf16x8 __attribute__((ext_vector_type(8)));
typedef float f32x4 __attribute__((ext_vector_type(4)));
typedef unsigned int u32x4 __attribute__((ext_vector_type(4)));
typedef unsigned int u32x2 __attribute__((ext_vector_type(2)));

#define SEQ 2048
#define MD 1024
#define DH 128

__device__ __forceinline__ unsigned short f2b(float f) {
  union { __hip_bfloat16 h; unsigned short u; } c;
  c.h = __float2bfloat16(f);
  return c.u;
}

// ---------------------------------------------------------------------------
// W prep: W[1024][128] f32 -> Wt[128][1024] bf16 per proj (LDS transpose).
// ---------------------------------------------------------------------------
__global__ __launch_bounds__(256) void wprep_kernel(
    const float* __restrict__ wq, const float* __restrict__ wk,
    const float* __restrict__ wv, __hip_bfloat16* __restrict__ wt)
{
  const int proj = blockIdx.x;   // 3
  const int part = blockIdx.y;   // 8 k-slabs of 128
  const float* __restrict__ w = (proj == 0) ? wq : ((proj == 1) ? wk : wv);
  __hip_bfloat16* __restrict__ o = wt + (size_t)proj * (128 * 1024);
  __shared__ __hip_bfloat16 t[128 * 130];  // [k_local][n], pad 130 vs bank conflicts
  const int tid = threadIdx.x;
#pragma unroll 4
  for (int i = 0; i < 64; ++i) {
    int idx = i * 256 + tid;
    int kl = idx >> 7, n = idx & 127;
    t[kl * 130 + n] = __float2bfloat16(w[(size_t)(part * 128 + kl) * 128 + n]);
  }
  __syncthreads();
#pragma unroll 4
  for (int j = 0; j < 64; ++j) {
    int idx = j * 256 + tid;
    int n = idx >> 7, kl = idx & 127;
    o[(size_t)n * 1024 + part * 128 + kl] = t[kl * 130 + n];
  }
}

// ---------------------------------------------------------------------------
// Projection GEMM, LDS-free: X[16384,1024] f32 x Wt[128,1024] bf16 -> bf16.
// M=64 per block, 4 waves (2x2), each wave 32 rows x 64 cols. No barriers:
// A fragments loaded f32 from HBM -> reg-convert; B fragments 16B from L2.
// grid (256, 3) = 768 blocks -> 12 waves/CU, free-running TLP hides latency.
// ---------------------------------------------------------------------------
__global__ __launch_bounds__(256) void proj_kernel(
    const float* __restrict__ xq, const float* __restrict__ xk, const float* __restrict__ xv,
    const __hip_bfloat16* __restrict__ wt,
    __hip_bfloat16* __restrict__ q_ws, __hip_bfloat16* __restrict__ k_ws,
    __hip_bfloat16* __restrict__ vt_ws)
{
  const int proj = blockIdx.y;
  const float* __restrict__ x = (proj == 0) ? xq : ((proj == 1) ? xk : xv);
  const __hip_bfloat16* __restrict__ w = wt + (size_t)proj * (128 * 1024);
  const int m0 = blockIdx.x * 64;
  const int tid = threadIdx.x;
  const int lane = tid & 63;
  const int wid = tid >> 6;
  const int ll = lane & 15, lh = lane >> 4;
  const int wr = (wid >> 1) * 32;   // wave row offset in tile
  const int wc = (wid & 1) * 64;    // wave col offset

  const f32x4 zero4 = {0.f, 0.f, 0.f, 0.f};
  f32x4 acc[2][4];
#pragma unroll
  for (int mi = 0; mi < 2; ++mi)
#pragma unroll
    for (int nf = 0; nf < 4; ++nf) acc[mi][nf] = zero4;

  const float* __restrict__ xr0 = x + (size_t)(m0 + wr + 0 + ll) * MD;
  const float* __restrict__ xr1 = x + (size_t)(m0 + wr + 16 + ll) * MD;
  const __hip_bfloat16* __restrict__ wb0 = w + (size_t)(wc + 0  + ll) * MD;
  const __hip_bfloat16* __restrict__ wb1 = w + (size_t)(wc + 16 + ll) * MD;
  const __hip_bfloat16* __restrict__ wb2 = w + (size_t)(wc + 32 + ll) * MD;
  const __hip_bfloat16* __restrict__ wb3 = w + (size_t)(wc + 48 + ll) * MD;

  for (int kt = 0; kt < 16; ++kt) {
    const int k0 = kt * 64 + lh * 8;
    // B fragments (L2-resident Wt), 8 x 16B
    bf16x8 wf[4][2];
#pragma unroll
    for (int kk = 0; kk < 2; ++kk) {
      wf[0][kk] = *reinterpret_cast<const bf16x8*>(wb0 + k0 + kk * 32);
      wf[1][kk] = *reinterpret_cast<const bf16x8*>(wb1 + k0 + kk * 32);
      wf[2][kk] = *reinterpret_cast<const bf16x8*>(wb2 + k0 + kk * 32);
      wf[3][kk] = *reinterpret_cast<const bf16x8*>(wb3 + k0 + kk * 32);
    }
    // A raw f32, 8 x 16B
    f32x4 ar[2][2][2];
#pragma unroll
    for (int mi = 0; mi < 2; ++mi) {
      const float* xr = mi ? xr1 : xr0;
#pragma unroll
      for (int kk = 0; kk < 2; ++kk) {
        ar[mi][kk][0] = *reinterpret_cast<const f32x4*>(xr + k0 + kk * 32);
        ar[mi][kk][1] = *reinterpret_cast<const f32x4*>(xr + k0 + kk * 32 + 4);
      }
    }
    // convert to bf16 fragments
    bf16x8 af[2][2];
#pragma unroll
    for (int mi = 0; mi < 2; ++mi)
#pragma unroll
      for (int kk = 0; kk < 2; ++kk) {
#pragma unroll
        for (int u = 0; u < 2; ++u)
#pragma unroll
          for (int j = 0; j < 4; ++j)
            af[mi][kk][u * 4 + j] = (short)f2b(ar[mi][kk][u][j]);
      }
    // MFMA
#pragma unroll
    for (int kk = 0; kk < 2; ++kk)
#pragma unroll
      for (int mi = 0; mi < 2; ++mi)
#pragma unroll
        for (int nf = 0; nf < 4; ++nf)
          acc[mi][nf] = __builtin_amdgcn_mfma_f32_16x16x32_bf16(
              af[mi][kk], wf[nf][kk], acc[mi][nf], 0, 0, 0);
  }

  // ---- epilogue ----
  if (proj < 2) {
    __hip_bfloat16* __restrict__ outp = proj ? k_ws : q_ws;
#pragma unroll
    for (int mi = 0; mi < 2; ++mi)
#pragma unroll
      for (int nf = 0; nf < 4; ++nf) {
        int col = wc + nf * 16 + ll;
#pragma unroll
        for (int r = 0; r < 4; ++r) {
          int row = m0 + wr + mi * 16 + lh * 4 + r;
          union { __hip_bfloat16 h; unsigned short u; } c;
          c.u = f2b(acc[mi][nf][r]);
          outp[(size_t)row * DH + col] = c.h;
        }
      }
  } else {
    // V transposed: vt[b][d][s], 4 consecutive s per lane -> 8B store
    const int b = m0 >> 11, sb = m0 & 2047;
#pragma unroll
    for (int mi = 0; mi < 2; ++mi)
#pragma unroll
      for (int nf = 0; nf < 4; ++nf) {
        int s = sb + wr + mi * 16 + lh * 4;
        int d = wc + nf * 16 + ll;
        u32x2 pk;
        pk[0] = (unsigned)f2b(acc[mi][nf][0]) | ((unsigned)f2b(acc[mi][nf][1]) << 16);
        pk[1] = (unsigned)f2b(acc[mi][nf][2]) | ((unsigned)f2b(acc[mi][nf][3]) << 16);
        *reinterpret_cast<u32x2*>(&vt_ws[((size_t)b * DH + d) * SEQ + s]) = pk;
      }
  }
}

// ---------------------------------------------------------------------------
// Causal flash attention: QBLK=32 (2 waves x 16 rows), KVBLK=64.
// grid (64, 8) = 512 blocks -> 2 blocks/CU so per-iter serial chains overlap.
// ---------------------------------------------------------------------------
__global__ __launch_bounds__(128) void attn_kernel(
    const __hip_bfloat16* __restrict__ q_ws, const __hip_bfloat16* __restrict__ k_ws,
    const __hip_bfloat16* __restrict__ vt_ws, float* __restrict__ out)
{
  const int qt = blockIdx.x;   // 32-row q tile (0..63)
  const int b  = blockIdx.y;
  const int tid = threadIdx.x;
  const int lane = tid & 63;
  const int wid = tid >> 6;    // 0..1
  const int ll = lane & 15;
  const int lh = lane >> 4;

  __shared__ __hip_bfloat16 Ks[64 * 128];  // [kv][d], swizzled
  __shared__ __hip_bfloat16 Vs[128 * 64];  // [d][kv], swizzled
  __shared__ float Ps[64 * 32];            // [kv][q] f32, swizzled; wave-private cols
  char* Ksb = (char*)Ks;
  char* Vsb = (char*)Vs;
  char* Psb = (char*)Ps;

  // Q fragments: wave owns q rows qt*32 + wid*16 .. +15
  bf16x8 qf[4];
  {
    const size_t qbase = ((size_t)b * SEQ + qt * 32 + wid * 16 + ll) * DH;
#pragma unroll
    for (int kk = 0; kk < 4; ++kk)
      qf[kk] = *reinterpret_cast<const bf16x8*>(&q_ws[qbase + kk * 32 + lh * 8]);
  }

  const f32x4 zero4 = {0.f, 0.f, 0.f, 0.f};
  float m_r[4], l_r[4];
  f32x4 oacc[8];
#pragma unroll
  for (int r = 0; r < 4; ++r) { m_r[r] = -INFINITY; l_r[r] = 0.f; }
#pragma unroll
  for (int nd = 0; nd < 8; ++nd) oacc[nd] = zero4;

  const float sl2e = 0.0883883476483184f * 1.4426950408889634f;  // 1/sqrt(128)*log2(e)

  const int niter = qt / 2 + 1;
  for (int it = 0; it < niter; ++it) {
    const int kv0 = it * 64;
    // ---- stage K tile [64][128] (16 KB, 128 threads) ----
#pragma unroll
    for (int i = 0; i < 8; ++i) {
      int id = tid + i * 128;
      int row = id >> 4;
      int cb = (id & 15) << 4;
      u32x4 v = *reinterpret_cast<const u32x4*>(
          &k_ws[((size_t)b * SEQ + kv0 + row) * DH + (cb >> 1)]);
      *reinterpret_cast<u32x4*>(Ksb + row * 256 + (cb ^ ((row & 7) << 4))) = v;
    }
    // ---- stage V^T tile [128][64] ----
#pragma unroll
    for (int i = 0; i < 8; ++i) {
      int id = tid + i * 128;
      int d = id >> 3;
      int cb = (id & 7) << 4;
      u32x4 v = *reinterpret_cast<const u32x4*>(
          &vt_ws[((size_t)b * DH + d) * SEQ + kv0 + (cb >> 1)]);
      *reinterpret_cast<u32x4*>(Vsb + d * 128 + (cb ^ ((d & 7) << 4))) = v;
    }
    __syncthreads();

    // ---- S = Q K^T (16 x 64 per wave) ----
    f32x4 sacc[4];
#pragma unroll
    for (int nf = 0; nf < 4; ++nf) sacc[nf] = zero4;
#pragma unroll
    for (int nf = 0; nf < 4; ++nf) {
      int row = nf * 16 + ll;
#pragma unroll
      for (int kk = 0; kk < 4; ++kk) {
        bf16x8 kf = *reinterpret_cast<bf16x8*>(
            Ksb + row * 256 + ((kk * 64 + lh * 16) ^ ((row & 7) << 4)));
        sacc[nf] = __builtin_amdgcn_mfma_f32_16x16x32_bf16(qf[kk], kf, sacc[nf], 0, 0, 0);
      }
    }

    // ---- scale + causal mask ----
    float sv[4][4];
    const int qr0 = qt * 32 + wid * 16 + lh * 4;
#pragma unroll
    for (int nf = 0; nf < 4; ++nf) {
      int kc = kv0 + nf * 16 + ll;
#pragma unroll
      for (int r = 0; r < 4; ++r) {
        float s = sacc[nf][r] * sl2e;
        sv[nf][r] = (kc <= qr0 + r) ? s : -INFINITY;
      }
    }

    // ---- online softmax per row (16-lane reduce) ----
    float p[4][4];
    float alpha[4];
#pragma unroll
    for (int r = 0; r < 4; ++r) {
      float mx = fmaxf(fmaxf(sv[0][r], sv[1][r]), fmaxf(sv[2][r], sv[3][r]));
#pragma unroll
      for (int off = 1; off < 16; off <<= 1)
        mx = fmaxf(mx, __shfl_xor(mx, off));
      float mnew = fmaxf(m_r[r], mx);
      float sum = 0.f;
#pragma unroll
      for (int nf = 0; nf < 4; ++nf) {
        float pv = exp2f(sv[nf][r] - mnew);
        p[nf][r] = pv;
        sum += pv;
      }
#pragma unroll
      for (int off = 1; off < 16; off <<= 1)
        sum += __shfl_xor(sum, off);
      alpha[r] = exp2f(m_r[r] - mnew);
      l_r[r] = l_r[r] * alpha[r] + sum;
      m_r[r] = mnew;
    }
#pragma unroll
    for (int nd = 0; nd < 8; ++nd)
#pragma unroll
      for (int r = 0; r < 4; ++r) oacc[nd][r] *= alpha[r];

    // ---- P^T -> LDS (wave-private columns) ----
#pragma unroll
    for (int nf = 0; nf < 4; ++nf) {
      int kv = nf * 16 + ll;
      f32x4 pv4 = {p[nf][0], p[nf][1], p[nf][2], p[nf][3]};
      *reinterpret_cast<f32x4*>(
          Psb + kv * 128 + ((wid * 64 + lh * 16) ^ ((kv & 7) << 4))) = pv4;
    }

    // ---- O += P V ----
#pragma unroll
    for (int kf = 0; kf < 2; ++kf) {
      float pf[8];
#pragma unroll
      for (int j = 0; j < 8; ++j) {
        int kv = kf * 32 + lh * 8 + j;
        pf[j] = *reinterpret_cast<float*>(
            Psb + kv * 128 + ((wid * 64 + ll * 4) ^ ((kv & 7) << 4)));
      }
      bf16x8 pa;
#pragma unroll
      for (int j = 0; j < 8; ++j) pa[j] = (short)f2b(pf[j]);
#pragma unroll
      for (int nd = 0; nd < 8; ++nd) {
        int d = nd * 16 + ll;
        bf16x8 vf = *reinterpret_cast<bf16x8*>(
            Vsb + d * 128 + ((kf * 64 + lh * 16) ^ ((d & 7) << 4)));
        oacc[nd] = __builtin_amdgcn_mfma_f32_16x16x32_bf16(pa, vf, oacc[nd], 0, 0, 0);
      }
    }
    __syncthreads();
  }

  // ---- epilogue ----
  float inv[4];
#pragma unroll
  for (int r = 0; r < 4; ++r) inv[r] = 1.0f / l_r[r];
#pragma unroll
  for (int nd = 0; nd < 8; ++nd) {
    int d = nd * 16 + ll;
#pragma unroll
    for (int r = 0; r < 4; ++r) {
      size_t row = (size_t)b * SEQ + qt * 32 + wid * 16 + lh * 4 + r;
      out[row * DH + d] = oacc[nd][r] * inv[r];
    }
  }
}

extern "C" void kernel_launch(void* const* d_in, const int* in_sizes, int n_in,
                              void* d_out, int out_size, void* d_ws, size_t ws_size,
                              hipStream_t stream) {
  const float* xq = (const float*)d_in[0];
  const float* xk = (const float*)d_in[1];
  const float* xv = (const float*)d_in[2];
  const float* wq = (const float*)d_in[3];
  const float* wk = (const float*)d_in[4];
  const float* wv = (const float*)d_in[5];

  __hip_bfloat16* q_ws = (__hip_bfloat16*)d_ws;
  __hip_bfloat16* k_ws = q_ws + (size_t)16384 * 128;
  __hip_bfloat16* vt_ws = k_ws + (size_t)16384 * 128;
  __hip_bfloat16* wt_ws = vt_ws + (size_t)16384 * 128;
  float* out = (float*)d_out;

  wprep_kernel<<<dim3(3, 8), 256, 0, stream>>>(wq, wk, wv, wt_ws);
  proj_kernel<<<dim3(256, 3), 256, 0, stream>>>(xq, xk, xv, wt_ws,
                                                q_ws, k_ws, vt_ws);
  attn_kernel<<<dim3(64, 8), 128, 0, stream>>>(q_ws, k_ws, vt_ws, out);
}

// Round 3
// 123.888 us; speedup vs baseline: 2.5481x; 2.5481x over previous
//
#include <hip/hip_runtime.h>
#include <hip/hip_bf16.h>
#include <math.h>

typedef short bf16x8 __attribute__((ext_vector_type(8)));
typedef float f32x4 __attribute__((ext_vector_type(4)));
typedef unsigned int u32x4 __attribute__((ext_vector_type(4)));
typedef unsigned int u32x2 __attribute__((ext_vector_type(2)));

#define SEQ 2048
#define MD 1024
#define DH 128

__device__ __forceinline__ unsigned f2b(float f) {
  union { __hip_bfloat16 h; unsigned short u; } c;
  c.h = __float2bfloat16(f);
  return (unsigned)c.u;
}

// ---------------------------------------------------------------------------
// W prep: W[1024][128] f32 -> Wt[128][1024] bf16 per proj (LDS transpose).
// ---------------------------------------------------------------------------
__global__ __launch_bounds__(256) void wprep_kernel(
    const float* __restrict__ wq, const float* __restrict__ wk,
    const float* __restrict__ wv, __hip_bfloat16* __restrict__ wt)
{
  const int proj = blockIdx.x;   // 3
  const int part = blockIdx.y;   // 8 k-slabs of 128
  const float* __restrict__ w = (proj == 0) ? wq : ((proj == 1) ? wk : wv);
  __hip_bfloat16* __restrict__ o = wt + (size_t)proj * (128 * 1024);
  __shared__ __hip_bfloat16 t[128 * 130];
  const int tid = threadIdx.x;
#pragma unroll 4
  for (int i = 0; i < 64; ++i) {
    int idx = i * 256 + tid;
    int kl = idx >> 7, n = idx & 127;
    t[kl * 130 + n] = __float2bfloat16(w[(size_t)(part * 128 + kl) * 128 + n]);
  }
  __syncthreads();
#pragma unroll 4
  for (int j = 0; j < 64; ++j) {
    int idx = j * 256 + tid;
    int n = idx >> 7, kl = idx & 127;
    o[(size_t)n * 1024 + part * 128 + kl] = t[kl * 130 + n];
  }
}

// ---------------------------------------------------------------------------
// Projection GEMM: X[16384,1024] f32 x Wt[128][1024] bf16 -> bf16.
// M=64 x N=128 tile, BK=64, 256 threads (4 waves, 2x2 of 32rows x 64cols).
// Double-buffered LDS (A 8KB + B 16KB per buf = 48KB total -> 3 blocks/CU).
// Coalesced f32x4 A loads (full 64B lines), reg-staged convert to bf16,
// XOR-swizzled LDS. Next-tile loads issued BEFORE compute (latency hiding).
// grid (256, 3) = 768 blocks.
// ---------------------------------------------------------------------------
__global__ __launch_bounds__(256) void proj_kernel(
    const float* __restrict__ xq, const float* __restrict__ xk, const float* __restrict__ xv,
    const __hip_bfloat16* __restrict__ wt,
    __hip_bfloat16* __restrict__ q_ws, __hip_bfloat16* __restrict__ k_ws,
    __hip_bfloat16* __restrict__ vt_ws)
{
  const int proj = blockIdx.y;
  const float* __restrict__ x = (proj == 0) ? xq : ((proj == 1) ? xk : xv);
  const __hip_bfloat16* __restrict__ w = wt + (size_t)proj * (128 * 1024);
  const int m0 = blockIdx.x * 64;
  const int tid = threadIdx.x;
  const int lane = tid & 63;
  const int wid = tid >> 6;
  const int ll = lane & 15, lh = lane >> 4;
  const int wr = (wid >> 1) * 32;   // wave row offset
  const int wc = (wid & 1) * 64;    // wave col offset

  __shared__ char lds[2][24 * 1024];  // per buf: A [64][128B] then B [128][128B]

  const f32x4 zero4 = {0.f, 0.f, 0.f, 0.f};
  f32x4 acc[2][4];
#pragma unroll
  for (int mi = 0; mi < 2; ++mi)
#pragma unroll
    for (int nf = 0; nf < 4; ++nf) acc[mi][nf] = zero4;

  // staging index precompute
  const int a_row = tid >> 4;            // 0..15 per 256-chunk step of 4
  const int a_c4  = (tid & 15) << 2;     // f32 col in k-tile
  const int b_n   = tid >> 3;            // 0..31 per step
  const int b_c   = (tid & 7) << 3;      // bf16 col in k-tile (8 elems = 16B)

  f32x4 ar[4];
  u32x4 br[4];

#define LD_TILES(KT)                                                          \
  {                                                                           \
    _Pragma("unroll")                                                         \
    for (int i = 0; i < 4; ++i)                                               \
      ar[i] = *reinterpret_cast<const f32x4*>(                                \
          &x[(size_t)(m0 + a_row + i * 16) * MD + (KT) * 64 + a_c4]);         \
    _Pragma("unroll")                                                         \
    for (int j = 0; j < 4; ++j)                                               \
      br[j] = *reinterpret_cast<const u32x4*>(                                \
          &w[(size_t)(b_n + j * 32) * MD + (KT) * 64 + b_c]);                 \
  }

#define ST_TILES(BUF)                                                         \
  {                                                                           \
    char* Asb = lds[BUF];                                                     \
    char* Bsb = lds[BUF] + 8192;                                              \
    _Pragma("unroll")                                                         \
    for (int i = 0; i < 4; ++i) {                                             \
      int row = a_row + i * 16;                                               \
      u32x2 pk;                                                               \
      pk[0] = f2b(ar[i][0]) | (f2b(ar[i][1]) << 16);                          \
      pk[1] = f2b(ar[i][2]) | (f2b(ar[i][3]) << 16);                          \
      *reinterpret_cast<u32x2*>(Asb + row * 128 +                             \
          ((a_c4 << 1) ^ ((row & 7) << 4))) = pk;                             \
    }                                                                         \
    _Pragma("unroll")                                                         \
    for (int j = 0; j < 4; ++j) {                                             \
      int n = b_n + j * 32;                                                   \
      *reinterpret_cast<u32x4*>(Bsb + n * 128 +                               \
          ((b_c << 1) ^ ((n & 7) << 4))) = br[j];                             \
    }                                                                         \
  }

  LD_TILES(0);
  ST_TILES(0);
  __syncthreads();

  for (int kt = 0; kt < 16; ++kt) {
    const int cur = kt & 1;
    if (kt < 15) LD_TILES(kt + 1);      // issue next-tile global loads early
    {
      char* Asb = lds[cur];
      char* Bsb = lds[cur] + 8192;
#pragma unroll
      for (int kk = 0; kk < 2; ++kk) {
        bf16x8 af[2], bfv[4];
#pragma unroll
        for (int mi = 0; mi < 2; ++mi) {
          int row = wr + mi * 16 + ll;
          af[mi] = *reinterpret_cast<bf16x8*>(
              Asb + row * 128 + ((kk * 64 + lh * 16) ^ ((row & 7) << 4)));
        }
#pragma unroll
        for (int nf = 0; nf < 4; ++nf) {
          int n = wc + nf * 16 + ll;
          bfv[nf] = *reinterpret_cast<bf16x8*>(
              Bsb + n * 128 + ((kk * 64 + lh * 16) ^ ((n & 7) << 4)));
        }
#pragma unroll
        for (int mi = 0; mi < 2; ++mi)
#pragma unroll
          for (int nf = 0; nf < 4; ++nf)
            acc[mi][nf] = __builtin_amdgcn_mfma_f32_16x16x32_bf16(
                af[mi], bfv[nf], acc[mi][nf], 0, 0, 0);
      }
    }
    if (kt < 15) ST_TILES(1 - cur);     // convert + write next buffer
    __syncthreads();
  }
#undef LD_TILES
#undef ST_TILES

  // ---- epilogue ----
  if (proj < 2) {
    __hip_bfloat16* __restrict__ outp = proj ? k_ws : q_ws;
#pragma unroll
    for (int mi = 0; mi < 2; ++mi)
#pragma unroll
      for (int nf = 0; nf < 4; ++nf) {
        int col = wc + nf * 16 + ll;
#pragma unroll
        for (int r = 0; r < 4; ++r) {
          int row = m0 + wr + mi * 16 + lh * 4 + r;
          union { __hip_bfloat16 h; unsigned short u; } c;
          c.u = (unsigned short)f2b(acc[mi][nf][r]);
          outp[(size_t)row * DH + col] = c.h;
        }
      }
  } else {
    // V transposed: vt[b][d][s], 4 consecutive s per lane -> 8B store
    const int b = m0 >> 11, sb = m0 & 2047;
#pragma unroll
    for (int mi = 0; mi < 2; ++mi)
#pragma unroll
      for (int nf = 0; nf < 4; ++nf) {
        int s = sb + wr + mi * 16 + lh * 4;
        int d = wc + nf * 16 + ll;
        u32x2 pk;
        pk[0] = f2b(acc[mi][nf][0]) | (f2b(acc[mi][nf][1]) << 16);
        pk[1] = f2b(acc[mi][nf][2]) | (f2b(acc[mi][nf][3]) << 16);
        *reinterpret_cast<u32x2*>(&vt_ws[((size_t)b * DH + d) * SEQ + s]) = pk;
      }
  }
}

// ---------------------------------------------------------------------------
// Causal flash attention — EXACT Round-1 version (known 36 us).
// q[16384][128], k[16384][128], vt[8][128][2048] bf16 -> out f32.
// QBLK=64 (4 waves x 16 rows), KVBLK=64, grid (32, 8).
// ---------------------------------------------------------------------------
__global__ __launch_bounds__(256) void attn_kernel(
    const __hip_bfloat16* __restrict__ q_ws, const __hip_bfloat16* __restrict__ k_ws,
    const __hip_bfloat16* __restrict__ vt_ws, float* __restrict__ out)
{
  const int qt = blockIdx.x;   // q tile (64 rows)
  const int b  = blockIdx.y;   // batch
  const int tid = threadIdx.x;
  const int lane = tid & 63;
  const int wid = tid >> 6;
  const int ll = lane & 15;
  const int lh = lane >> 4;

  __shared__ __hip_bfloat16 Ks[64 * 128];  // [kv][d], swizzled
  __shared__ __hip_bfloat16 Vs[128 * 64];  // [d][kv], swizzled
  __shared__ float Ps[64 * 64];            // [kv][q] f32, swizzled; wave-private cols
  char* Ksb = (char*)Ks;
  char* Vsb = (char*)Vs;
  char* Psb = (char*)Ps;

  bf16x8 qf[4];
  {
    const size_t qbase = ((size_t)b * SEQ + qt * 64 + wid * 16 + ll) * DH;
#pragma unroll
    for (int kk = 0; kk < 4; ++kk)
      qf[kk] = *reinterpret_cast<const bf16x8*>(&q_ws[qbase + kk * 32 + lh * 8]);
  }

  const f32x4 zero4 = {0.f, 0.f, 0.f, 0.f};
  float m_r[4], l_r[4];
  f32x4 oacc[8];
#pragma unroll
  for (int r = 0; r < 4; ++r) { m_r[r] = -INFINITY; l_r[r] = 0.f; }
#pragma unroll
  for (int nd = 0; nd < 8; ++nd) oacc[nd] = zero4;

  const float sl2e = 0.0883883476483184f * 1.4426950408889634f;

  const int niter = qt + 1;
  for (int it = 0; it < niter; ++it) {
    const int kv0 = it * 64;
#pragma unroll
    for (int i = 0; i < 4; ++i) {
      int id = tid + i * 256;
      int row = id >> 4;
      int cb = (id & 15) << 4;
      u32x4 v = *reinterpret_cast<const u32x4*>(
          &k_ws[((size_t)b * SEQ + kv0 + row) * DH + (cb >> 1)]);
      *reinterpret_cast<u32x4*>(Ksb + row * 256 + (cb ^ ((row & 7) << 4))) = v;
    }
#pragma unroll
    for (int i = 0; i < 4; ++i) {
      int id = tid + i * 256;
      int d = id >> 3;
      int cb = (id & 7) << 4;
      u32x4 v = *reinterpret_cast<const u32x4*>(
          &vt_ws[((size_t)b * DH + d) * SEQ + kv0 + (cb >> 1)]);
      *reinterpret_cast<u32x4*>(Vsb + d * 128 + (cb ^ ((d & 7) << 4))) = v;
    }
    __syncthreads();

    f32x4 sacc[4];
#pragma unroll
    for (int nf = 0; nf < 4; ++nf) sacc[nf] = zero4;
#pragma unroll
    for (int nf = 0; nf < 4; ++nf) {
      int row = nf * 16 + ll;
#pragma unroll
      for (int kk = 0; kk < 4; ++kk) {
        bf16x8 kf = *reinterpret_cast<bf16x8*>(
            Ksb + row * 256 + ((kk * 64 + lh * 16) ^ ((row & 7) << 4)));
        sacc[nf] = __builtin_amdgcn_mfma_f32_16x16x32_bf16(qf[kk], kf, sacc[nf], 0, 0, 0);
      }
    }

    float sv[4][4];
    const int qr0 = qt * 64 + wid * 16 + lh * 4;
#pragma unroll
    for (int nf = 0; nf < 4; ++nf) {
      int kc = kv0 + nf * 16 + ll;
#pragma unroll
      for (int r = 0; r < 4; ++r) {
        float s = sacc[nf][r] * sl2e;
        sv[nf][r] = (kc <= qr0 + r) ? s : -INFINITY;
      }
    }

    float p[4][4];
    float alpha[4];
#pragma unroll
    for (int r = 0; r < 4; ++r) {
      float mx = fmaxf(fmaxf(sv[0][r], sv[1][r]), fmaxf(sv[2][r], sv[3][r]));
#pragma unroll
      for (int off = 1; off < 16; off <<= 1)
        mx = fmaxf(mx, __shfl_xor(mx, off));
      float mnew = fmaxf(m_r[r], mx);
      float sum = 0.f;
#pragma unroll
      for (int nf = 0; nf < 4; ++nf) {
        float pv = exp2f(sv[nf][r] - mnew);
        p[nf][r] = pv;
        sum += pv;
      }
#pragma unroll
      for (int off = 1; off < 16; off <<= 1)
        sum += __shfl_xor(sum, off);
      alpha[r] = exp2f(m_r[r] - mnew);
      l_r[r] = l_r[r] * alpha[r] + sum;
      m_r[r] = mnew;
    }
#pragma unroll
    for (int nd = 0; nd < 8; ++nd)
#pragma unroll
      for (int r = 0; r < 4; ++r) oacc[nd][r] *= alpha[r];

#pragma unroll
    for (int nf = 0; nf < 4; ++nf) {
      int kv = nf * 16 + ll;
      f32x4 pv4 = {p[nf][0], p[nf][1], p[nf][2], p[nf][3]};
      *reinterpret_cast<f32x4*>(
          Psb + kv * 256 + ((wid * 64 + lh * 16) ^ ((kv & 7) << 4))) = pv4;
    }

#pragma unroll
    for (int kf = 0; kf < 2; ++kf) {
      float pf[8];
#pragma unroll
      for (int j = 0; j < 8; ++j) {
        int kv = kf * 32 + lh * 8 + j;
        pf[j] = *reinterpret_cast<float*>(
            Psb + kv * 256 + ((wid * 64 + ll * 4) ^ ((kv & 7) << 4)));
      }
      bf16x8 pa;
#pragma unroll
      for (int j = 0; j < 8; ++j) pa[j] = (short)f2b(pf[j]);
#pragma unroll
      for (int nd = 0; nd < 8; ++nd) {
        int d = nd * 16 + ll;
        bf16x8 vf = *reinterpret_cast<bf16x8*>(
            Vsb + d * 128 + ((kf * 64 + lh * 16) ^ ((d & 7) << 4)));
        oacc[nd] = __builtin_amdgcn_mfma_f32_16x16x32_bf16(pa, vf, oacc[nd], 0, 0, 0);
      }
    }
    __syncthreads();
  }

  float inv[4];
#pragma unroll
  for (int r = 0; r < 4; ++r) inv[r] = 1.0f / l_r[r];
#pragma unroll
  for (int nd = 0; nd < 8; ++nd) {
    int d = nd * 16 + ll;
#pragma unroll
    for (int r = 0; r < 4; ++r) {
      size_t row = (size_t)b * SEQ + qt * 64 + wid * 16 + lh * 4 + r;
      out[row * DH + d] = oacc[nd][r] * inv[r];
    }
  }
}

extern "C" void kernel_launch(void* const* d_in, const int* in_sizes, int n_in,
                              void* d_out, int out_size, void* d_ws, size_t ws_size,
                              hipStream_t stream) {
  const float* xq = (const float*)d_in[0];
  const float* xk = (const float*)d_in[1];
  const float* xv = (const float*)d_in[2];
  const float* wq = (const float*)d_in[3];
  const float* wk = (const float*)d_in[4];
  const float* wv = (const float*)d_in[5];

  __hip_bfloat16* q_ws = (__hip_bfloat16*)d_ws;
  __hip_bfloat16* k_ws = q_ws + (size_t)16384 * 128;
  __hip_bfloat16* vt_ws = k_ws + (size_t)16384 * 128;
  __hip_bfloat16* wt_ws = vt_ws + (size_t)16384 * 128;
  float* out = (float*)d_out;

  wprep_kernel<<<dim3(3, 8), 256, 0, stream>>>(wq, wk, wv, wt_ws);
  proj_kernel<<<dim3(256, 3), 256, 0, stream>>>(xq, xk, xv, wt_ws,
                                                q_ws, k_ws, vt_ws);
  attn_kernel<<<dim3(32, 8), 256, 0, stream>>>(q_ws, k_ws, vt_ws, out);
}

// Round 4
// 103.100 us; speedup vs baseline: 3.0619x; 1.2016x over previous
//
#include <hip/hip_runtime.h>
#include <hip/hip_bf16.h>
#include <math.h>

typedef short bf16x8 __attribute__((ext_vector_type(8)));
typedef float f32x4 __attribute__((ext_vector_type(4)));
typedef unsigned int u32x4 __attribute__((ext_vector_type(4)));
typedef unsigned int u32x2 __attribute__((ext_vector_type(2)));

#define SEQ 2048
#define MD 1024
#define DH 128

__device__ __forceinline__ unsigned f2b(float f) {
  union { __hip_bfloat16 h; unsigned short u; } c;
  c.h = __float2bfloat16(f);
  return (unsigned)c.u;
}

// ---------------------------------------------------------------------------
// W prep: W[1024][128] f32 -> Wt[128][1024] bf16 per proj (LDS transpose).
// ---------------------------------------------------------------------------
__global__ __launch_bounds__(256) void wprep_kernel(
    const float* __restrict__ wq, const float* __restrict__ wk,
    const float* __restrict__ wv, __hip_bfloat16* __restrict__ wt)
{
  const int proj = blockIdx.x;   // 3
  const int part = blockIdx.y;   // 8 k-slabs of 128
  const float* __restrict__ w = (proj == 0) ? wq : ((proj == 1) ? wk : wv);
  __hip_bfloat16* __restrict__ o = wt + (size_t)proj * (128 * 1024);
  __shared__ __hip_bfloat16 t[128 * 130];
  const int tid = threadIdx.x;
#pragma unroll 4
  for (int i = 0; i < 64; ++i) {
    int idx = i * 256 + tid;
    int kl = idx >> 7, n = idx & 127;
    t[kl * 130 + n] = __float2bfloat16(w[(size_t)(part * 128 + kl) * 128 + n]);
  }
  __syncthreads();
#pragma unroll 4
  for (int j = 0; j < 64; ++j) {
    int idx = j * 256 + tid;
    int n = idx >> 7, kl = idx & 127;
    o[(size_t)n * 1024 + part * 128 + kl] = t[kl * 130 + n];
  }
}

// ---------------------------------------------------------------------------
// Projection GEMM (unchanged from Round 3: ~38-40 us, near HBM floor).
// M=64 x N=128 tile, BK=64, 256 threads, double-buffered swizzled LDS.
// ---------------------------------------------------------------------------
__global__ __launch_bounds__(256) void proj_kernel(
    const float* __restrict__ xq, const float* __restrict__ xk, const float* __restrict__ xv,
    const __hip_bfloat16* __restrict__ wt,
    __hip_bfloat16* __restrict__ q_ws, __hip_bfloat16* __restrict__ k_ws,
    __hip_bfloat16* __restrict__ vt_ws)
{
  const int proj = blockIdx.y;
  const float* __restrict__ x = (proj == 0) ? xq : ((proj == 1) ? xk : xv);
  const __hip_bfloat16* __restrict__ w = wt + (size_t)proj * (128 * 1024);
  const int m0 = blockIdx.x * 64;
  const int tid = threadIdx.x;
  const int lane = tid & 63;
  const int wid = tid >> 6;
  const int ll = lane & 15, lh = lane >> 4;
  const int wr = (wid >> 1) * 32;
  const int wc = (wid & 1) * 64;

  __shared__ char lds[2][24 * 1024];

  const f32x4 zero4 = {0.f, 0.f, 0.f, 0.f};
  f32x4 acc[2][4];
#pragma unroll
  for (int mi = 0; mi < 2; ++mi)
#pragma unroll
    for (int nf = 0; nf < 4; ++nf) acc[mi][nf] = zero4;

  const int a_row = tid >> 4;
  const int a_c4  = (tid & 15) << 2;
  const int b_n   = tid >> 3;
  const int b_c   = (tid & 7) << 3;

  f32x4 ar[4];
  u32x4 br[4];

#define LD_TILES(KT)                                                          \
  {                                                                           \
    _Pragma("unroll")                                                         \
    for (int i = 0; i < 4; ++i)                                               \
      ar[i] = *reinterpret_cast<const f32x4*>(                                \
          &x[(size_t)(m0 + a_row + i * 16) * MD + (KT) * 64 + a_c4]);         \
    _Pragma("unroll")                                                         \
    for (int j = 0; j < 4; ++j)                                               \
      br[j] = *reinterpret_cast<const u32x4*>(                                \
          &w[(size_t)(b_n + j * 32) * MD + (KT) * 64 + b_c]);                 \
  }

#define ST_TILES(BUF)                                                         \
  {                                                                           \
    char* Asb = lds[BUF];                                                     \
    char* Bsb = lds[BUF] + 8192;                                              \
    _Pragma("unroll")                                                         \
    for (int i = 0; i < 4; ++i) {                                             \
      int row = a_row + i * 16;                                               \
      u32x2 pk;                                                               \
      pk[0] = f2b(ar[i][0]) | (f2b(ar[i][1]) << 16);                          \
      pk[1] = f2b(ar[i][2]) | (f2b(ar[i][3]) << 16);                          \
      *reinterpret_cast<u32x2*>(Asb + row * 128 +                             \
          ((a_c4 << 1) ^ ((row & 7) << 4))) = pk;                             \
    }                                                                         \
    _Pragma("unroll")                                                         \
    for (int j = 0; j < 4; ++j) {                                             \
      int n = b_n + j * 32;                                                   \
      *reinterpret_cast<u32x4*>(Bsb + n * 128 +                               \
          ((b_c << 1) ^ ((n & 7) << 4))) = br[j];                             \
    }                                                                         \
  }

  LD_TILES(0);
  ST_TILES(0);
  __syncthreads();

  for (int kt = 0; kt < 16; ++kt) {
    const int cur = kt & 1;
    if (kt < 15) LD_TILES(kt + 1);
    {
      char* Asb = lds[cur];
      char* Bsb = lds[cur] + 8192;
#pragma unroll
      for (int kk = 0; kk < 2; ++kk) {
        bf16x8 af[2], bfv[4];
#pragma unroll
        for (int mi = 0; mi < 2; ++mi) {
          int row = wr + mi * 16 + ll;
          af[mi] = *reinterpret_cast<bf16x8*>(
              Asb + row * 128 + ((kk * 64 + lh * 16) ^ ((row & 7) << 4)));
        }
#pragma unroll
        for (int nf = 0; nf < 4; ++nf) {
          int n = wc + nf * 16 + ll;
          bfv[nf] = *reinterpret_cast<bf16x8*>(
              Bsb + n * 128 + ((kk * 64 + lh * 16) ^ ((n & 7) << 4)));
        }
#pragma unroll
        for (int mi = 0; mi < 2; ++mi)
#pragma unroll
          for (int nf = 0; nf < 4; ++nf)
            acc[mi][nf] = __builtin_amdgcn_mfma_f32_16x16x32_bf16(
                af[mi], bfv[nf], acc[mi][nf], 0, 0, 0);
      }
    }
    if (kt < 15) ST_TILES(1 - cur);
    __syncthreads();
  }
#undef LD_TILES
#undef ST_TILES

  if (proj < 2) {
    __hip_bfloat16* __restrict__ outp = proj ? k_ws : q_ws;
#pragma unroll
    for (int mi = 0; mi < 2; ++mi)
#pragma unroll
      for (int nf = 0; nf < 4; ++nf) {
        int col = wc + nf * 16 + ll;
#pragma unroll
        for (int r = 0; r < 4; ++r) {
          int row = m0 + wr + mi * 16 + lh * 4 + r;
          union { __hip_bfloat16 h; unsigned short u; } c;
          c.u = (unsigned short)f2b(acc[mi][nf][r]);
          outp[(size_t)row * DH + col] = c.h;
        }
      }
  } else {
    const int b = m0 >> 11, sb = m0 & 2047;
#pragma unroll
    for (int mi = 0; mi < 2; ++mi)
#pragma unroll
      for (int nf = 0; nf < 4; ++nf) {
        int s = sb + wr + mi * 16 + lh * 4;
        int d = wc + nf * 16 + ll;
        u32x2 pk;
        pk[0] = f2b(acc[mi][nf][0]) | (f2b(acc[mi][nf][1]) << 16);
        pk[1] = f2b(acc[mi][nf][2]) | (f2b(acc[mi][nf][3]) << 16);
        *reinterpret_cast<u32x2*>(&vt_ws[((size_t)b * DH + d) * SEQ + s]) = pk;
      }
  }
}

// ---------------------------------------------------------------------------
// Split-KV causal flash attention. QBLK=64 (4 waves x 16 rows), KVBLK=64,
// KV chunk = 8 KVBLK iterations (512 kv). Per batch: 80 chunk-blocks
// (qt 0-7: 1 chunk, 8-15: 2, 16-23: 3, 24-31: 4) -> grid (80, 8) = 640
// blocks, max 8 iters each (balanced, 2.5 blocks/CU). Writes unnormalized
// partials (O_hat f32 [slot][64][128], m/l f32 [slot][64][2]).
// ---------------------------------------------------------------------------
__global__ __launch_bounds__(256) void attn_kernel(
    const __hip_bfloat16* __restrict__ q_ws, const __hip_bfloat16* __restrict__ k_ws,
    const __hip_bfloat16* __restrict__ vt_ws,
    float* __restrict__ pO, float* __restrict__ pml)
{
  // decode chunk-block -> (qt, c)
  const int s = blockIdx.x;
  int qt, c;
  if (s < 8)       { qt = s;                c = 0; }
  else if (s < 24) { int u = s - 8;  qt = 8 + (u >> 1);  c = u & 1; }
  else if (s < 48) { int u = s - 24; qt = 16 + u / 3;    c = u % 3; }
  else             { int u = s - 48; qt = 24 + (u >> 2); c = u & 3; }
  const int b = blockIdx.y;
  const int g = qt >> 3;
  const int slot = b * 80 + (4 * g * (g + 1) + (g + 1) * (qt & 7)) + c;

  const int tid = threadIdx.x;
  const int lane = tid & 63;
  const int wid = tid >> 6;
  const int ll = lane & 15;
  const int lh = lane >> 4;

  __shared__ __hip_bfloat16 Ks[64 * 128];
  __shared__ __hip_bfloat16 Vs[128 * 64];
  __shared__ float Ps[64 * 64];
  char* Ksb = (char*)Ks;
  char* Vsb = (char*)Vs;
  char* Psb = (char*)Ps;

  bf16x8 qf[4];
  {
    const size_t qbase = ((size_t)b * SEQ + qt * 64 + wid * 16 + ll) * DH;
#pragma unroll
    for (int kk = 0; kk < 4; ++kk)
      qf[kk] = *reinterpret_cast<const bf16x8*>(&q_ws[qbase + kk * 32 + lh * 8]);
  }

  const f32x4 zero4 = {0.f, 0.f, 0.f, 0.f};
  float m_r[4], l_r[4];
  f32x4 oacc[8];
#pragma unroll
  for (int r = 0; r < 4; ++r) { m_r[r] = -INFINITY; l_r[r] = 0.f; }
#pragma unroll
  for (int nd = 0; nd < 8; ++nd) oacc[nd] = zero4;

  const float sl2e = 0.0883883476483184f * 1.4426950408889634f;

  const int it0 = c * 8;
  const int it1 = min(qt + 1, it0 + 8);
  for (int it = it0; it < it1; ++it) {
    const int kv0 = it * 64;
#pragma unroll
    for (int i = 0; i < 4; ++i) {
      int id = tid + i * 256;
      int row = id >> 4;
      int cb = (id & 15) << 4;
      u32x4 v = *reinterpret_cast<const u32x4*>(
          &k_ws[((size_t)b * SEQ + kv0 + row) * DH + (cb >> 1)]);
      *reinterpret_cast<u32x4*>(Ksb + row * 256 + (cb ^ ((row & 7) << 4))) = v;
    }
#pragma unroll
    for (int i = 0; i < 4; ++i) {
      int id = tid + i * 256;
      int d = id >> 3;
      int cb = (id & 7) << 4;
      u32x4 v = *reinterpret_cast<const u32x4*>(
          &vt_ws[((size_t)b * DH + d) * SEQ + kv0 + (cb >> 1)]);
      *reinterpret_cast<u32x4*>(Vsb + d * 128 + (cb ^ ((d & 7) << 4))) = v;
    }
    __syncthreads();

    f32x4 sacc[4];
#pragma unroll
    for (int nf = 0; nf < 4; ++nf) sacc[nf] = zero4;
#pragma unroll
    for (int nf = 0; nf < 4; ++nf) {
      int row = nf * 16 + ll;
#pragma unroll
      for (int kk = 0; kk < 4; ++kk) {
        bf16x8 kf = *reinterpret_cast<bf16x8*>(
            Ksb + row * 256 + ((kk * 64 + lh * 16) ^ ((row & 7) << 4)));
        sacc[nf] = __builtin_amdgcn_mfma_f32_16x16x32_bf16(qf[kk], kf, sacc[nf], 0, 0, 0);
      }
    }

    float sv[4][4];
    const int qr0 = qt * 64 + wid * 16 + lh * 4;
#pragma unroll
    for (int nf = 0; nf < 4; ++nf) {
      int kc = kv0 + nf * 16 + ll;
#pragma unroll
      for (int r = 0; r < 4; ++r) {
        float sc = sacc[nf][r] * sl2e;
        sv[nf][r] = (kc <= qr0 + r) ? sc : -INFINITY;
      }
    }

    float p[4][4];
    float alpha[4];
#pragma unroll
    for (int r = 0; r < 4; ++r) {
      float mx = fmaxf(fmaxf(sv[0][r], sv[1][r]), fmaxf(sv[2][r], sv[3][r]));
#pragma unroll
      for (int off = 1; off < 16; off <<= 1)
        mx = fmaxf(mx, __shfl_xor(mx, off));
      float mnew = fmaxf(m_r[r], mx);
      float sum = 0.f;
#pragma unroll
      for (int nf = 0; nf < 4; ++nf) {
        float pv = exp2f(sv[nf][r] - mnew);
        p[nf][r] = pv;
        sum += pv;
      }
#pragma unroll
      for (int off = 1; off < 16; off <<= 1)
        sum += __shfl_xor(sum, off);
      alpha[r] = exp2f(m_r[r] - mnew);
      l_r[r] = l_r[r] * alpha[r] + sum;
      m_r[r] = mnew;
    }
#pragma unroll
    for (int nd = 0; nd < 8; ++nd)
#pragma unroll
      for (int r = 0; r < 4; ++r) oacc[nd][r] *= alpha[r];

#pragma unroll
    for (int nf = 0; nf < 4; ++nf) {
      int kv = nf * 16 + ll;
      f32x4 pv4 = {p[nf][0], p[nf][1], p[nf][2], p[nf][3]};
      *reinterpret_cast<f32x4*>(
          Psb + kv * 256 + ((wid * 64 + lh * 16) ^ ((kv & 7) << 4))) = pv4;
    }

#pragma unroll
    for (int kf = 0; kf < 2; ++kf) {
      float pf[8];
#pragma unroll
      for (int j = 0; j < 8; ++j) {
        int kv = kf * 32 + lh * 8 + j;
        pf[j] = *reinterpret_cast<float*>(
            Psb + kv * 256 + ((wid * 64 + ll * 4) ^ ((kv & 7) << 4)));
      }
      bf16x8 pa;
#pragma unroll
      for (int j = 0; j < 8; ++j) pa[j] = (short)f2b(pf[j]);
#pragma unroll
      for (int nd = 0; nd < 8; ++nd) {
        int d = nd * 16 + ll;
        bf16x8 vf = *reinterpret_cast<bf16x8*>(
            Vsb + d * 128 + ((kf * 64 + lh * 16) ^ ((d & 7) << 4)));
        oacc[nd] = __builtin_amdgcn_mfma_f32_16x16x32_bf16(pa, vf, oacc[nd], 0, 0, 0);
      }
    }
    __syncthreads();
  }

  // ---- epilogue: write unnormalized partials ----
  float* __restrict__ po = pO + (size_t)slot * (64 * 128);
#pragma unroll
  for (int nd = 0; nd < 8; ++nd) {
    int d = nd * 16 + ll;
#pragma unroll
    for (int r = 0; r < 4; ++r) {
      int row = wid * 16 + lh * 4 + r;
      po[row * 128 + d] = oacc[nd][r];
    }
  }
  if (ll == 0) {
    float* __restrict__ pm = pml + (size_t)slot * 128;
#pragma unroll
    for (int r = 0; r < 4; ++r) {
      int row = wid * 16 + lh * 4 + r;
      pm[row * 2 + 0] = m_r[r];
      pm[row * 2 + 1] = l_r[r];
    }
  }
}

// ---------------------------------------------------------------------------
// Combine: merge <=4 partials per (b, qt) with log-sum-exp weights.
// grid (32, 8), 256 threads: thread -> (row = tid>>2, col quarter = tid&3).
// ---------------------------------------------------------------------------
__global__ __launch_bounds__(256) void combine_kernel(
    const float* __restrict__ pO, const float* __restrict__ pml,
    float* __restrict__ out)
{
  const int qt = blockIdx.x;
  const int b = blockIdx.y;
  const int g = qt >> 3;
  const int nc = g + 1;
  const size_t slot0 = (size_t)b * 80 + (4 * g * (g + 1) + (g + 1) * (qt & 7));
  const int tid = threadIdx.x;
  const int r = tid >> 2;
  const int q4 = tid & 3;

  float m[4], l[4];
#pragma unroll
  for (int i = 0; i < 4; ++i) {
    if (i < nc) {
      m[i] = pml[(slot0 + i) * 128 + r * 2 + 0];
      l[i] = pml[(slot0 + i) * 128 + r * 2 + 1];
    } else { m[i] = -INFINITY; l[i] = 0.f; }
  }
  float M = fmaxf(fmaxf(m[0], m[1]), fmaxf(m[2], m[3]));
  float w[4];
  float L = 0.f;
#pragma unroll
  for (int i = 0; i < 4; ++i) {
    w[i] = (i < nc) ? exp2f(m[i] - M) : 0.f;
    L += l[i] * w[i];
  }
  const float inv = 1.0f / L;

  const size_t orow = ((size_t)b * SEQ + qt * 64 + r) * DH;
#pragma unroll
  for (int j = 0; j < 8; ++j) {
    const int col = q4 * 32 + j * 4;
    f32x4 acc = {0.f, 0.f, 0.f, 0.f};
#pragma unroll
    for (int i = 0; i < 4; ++i) {
      if (i < nc) {
        f32x4 v = *reinterpret_cast<const f32x4*>(
            &pO[(slot0 + i) * (64 * 128) + r * 128 + col]);
#pragma unroll
        for (int u = 0; u < 4; ++u) acc[u] += v[u] * w[i];
      }
    }
#pragma unroll
    for (int u = 0; u < 4; ++u) acc[u] *= inv;
    *reinterpret_cast<f32x4*>(&out[orow + col]) = acc;
  }
}

extern "C" void kernel_launch(void* const* d_in, const int* in_sizes, int n_in,
                              void* d_out, int out_size, void* d_ws, size_t ws_size,
                              hipStream_t stream) {
  const float* xq = (const float*)d_in[0];
  const float* xk = (const float*)d_in[1];
  const float* xv = (const float*)d_in[2];
  const float* wq = (const float*)d_in[3];
  const float* wk = (const float*)d_in[4];
  const float* wv = (const float*)d_in[5];

  __hip_bfloat16* q_ws = (__hip_bfloat16*)d_ws;
  __hip_bfloat16* k_ws = q_ws + (size_t)16384 * 128;
  __hip_bfloat16* vt_ws = k_ws + (size_t)16384 * 128;
  __hip_bfloat16* wt_ws = vt_ws + (size_t)16384 * 128;
  // f32 partial buffers after the bf16 region (byte offset 13,369,344)
  float* pO = (float*)((char*)d_ws + 13369344);            // 640*64*128 f32 = 20 MB
  float* pml = (float*)((char*)d_ws + 13369344 + 20971520); // 640*64*2 f32 = 320 KB
  float* out = (float*)d_out;

  wprep_kernel<<<dim3(3, 8), 256, 0, stream>>>(wq, wk, wv, wt_ws);
  proj_kernel<<<dim3(256, 3), 256, 0, stream>>>(xq, xk, xv, wt_ws,
                                                q_ws, k_ws, vt_ws);
  attn_kernel<<<dim3(80, 8), 256, 0, stream>>>(q_ws, k_ws, vt_ws, pO, pml);
  combine_kernel<<<dim3(32, 8), 256, 0, stream>>>(pO, pml, out);
}